// Round 4
// baseline (339.727 us; speedup 1.0000x reference)
//
#include <hip/hip_runtime.h>

#define B  16
#define N  256
#define F  128
#define NB 32
#define INF_F 1000000000.0f

__device__ __forceinline__ float xf(float v, int gi, int gk) {
    // where(adj>0, adj, INF) then diag=0 (diag wins), exactly like reference
    return (gi == gk) ? 0.0f : ((v > 0.0f) ? v : INF_F);
}
__device__ __forceinline__ float4 ld4(const float* p) { return *(const float4*)p; }
__device__ __forceinline__ float4 min4(float4 a, float4 b) {
    return make_float4(fminf(a.x, b.x), fminf(a.y, b.y),
                       fminf(a.z, b.z), fminf(a.w, b.w));
}

// ---------------------------------------------------------------------------
// min-plus squaring, K-split x4. Block (b,bi,bj,ks): 64 threads (1 wave),
// computes P_ks[i,j] = min_{k in [ks*64,(ks+1)*64)} S[i,k] + S[k,j]
// with S = XFORM(adj) (FIRST) or min(P0..P3) of the previous step (exact).
// 64x64 tile, 8x8 acc per lane. A stored [i][k] XOR-quad-swizzled so the
// uniform-k b128 reads spread across banks by ly; B stored [k][j] linear.
// 1 wave/block -> no inter-wave barriers; 4 blocks/CU = 1 wave/SIMD.
// ---------------------------------------------------------------------------
template<bool FIRST>
__global__ __launch_bounds__(64) void k_minplus(const float* __restrict__ P0,
                                                const float* __restrict__ P1,
                                                const float* __restrict__ P2,
                                                const float* __restrict__ P3,
                                                float* __restrict__ Out) {
    int blk = blockIdx.x;            // b*64 + bi*16 + bj*4 + ks, 1024 total
    int ks = blk & 3;
    int bj = (blk >> 2) & 3;
    int bi = (blk >> 4) & 3;
    int b  = blk >> 6;
    const int bofs = b * N * N;
    const int kb = ks * 64, bi64 = bi * 64, bj64 = bj * 64;

    __shared__ __align__(16) float As[64 * 64];   // [i][k^swz(i)]
    __shared__ __align__(16) float Bs[64 * 64];   // [k][j]

    int tid = threadIdx.x;
    int ly = tid >> 3, lx = tid & 7;

    // ---- stage both 64x64 tiles (A: rows bi64.., k-chunk; B: k-chunk, cols bj64..)
#pragma unroll
    for (int u = 0; u < 16; ++u) {
        int lin4 = u * 64 + tid;
        int r  = lin4 >> 4;               // 0..63
        int c4 = (lin4 & 15) << 2;        // 0,4,..,60
        int aidx = bofs + (bi64 + r) * N + kb + c4;
        int bidx = bofs + (kb + r) * N + bj64 + c4;
        float4 av, bv;
        if (FIRST) {
            av = ld4(P0 + aidx);
            bv = ld4(P0 + bidx);
            av.x = xf(av.x, bi64 + r, kb + c4 + 0);
            av.y = xf(av.y, bi64 + r, kb + c4 + 1);
            av.z = xf(av.z, bi64 + r, kb + c4 + 2);
            av.w = xf(av.w, bi64 + r, kb + c4 + 3);
            bv.x = xf(bv.x, kb + r, bj64 + c4 + 0);
            bv.y = xf(bv.y, kb + r, bj64 + c4 + 1);
            bv.z = xf(bv.z, kb + r, bj64 + c4 + 2);
            bv.w = xf(bv.w, kb + r, bj64 + c4 + 3);
        } else {
            av = min4(min4(ld4(P0 + aidx), ld4(P1 + aidx)),
                      min4(ld4(P2 + aidx), ld4(P3 + aidx)));
            bv = min4(min4(ld4(P0 + bidx), ld4(P1 + bidx)),
                      min4(ld4(P2 + bidx), ld4(P3 + bidx)));
        }
        int swz = (r >> 3) << 2;
        *(float4*)&As[r * 64 + (c4 ^ swz)] = av;
        *(float4*)&Bs[r * 64 + c4] = bv;
    }
    __syncthreads();   // single wave: compiles to a waitcnt, no real barrier cost

    float acc[8][8];
#pragma unroll
    for (int r = 0; r < 8; ++r)
#pragma unroll
        for (int c = 0; c < 8; ++c) acc[r][c] = 3.0e38f;

    int swzly = ly << 2;
    int arow = ly * 8;      // first of this lane's 8 rows
    int bcol = lx * 8;      // first of this lane's 8 cols

#define COLS(rr, a, q0, q1)                                                    \
    acc[rr][0] = fminf(acc[rr][0], (a) + q0.x);                                \
    acc[rr][1] = fminf(acc[rr][1], (a) + q0.y);                                \
    acc[rr][2] = fminf(acc[rr][2], (a) + q0.z);                                \
    acc[rr][3] = fminf(acc[rr][3], (a) + q0.w);                                \
    acc[rr][4] = fminf(acc[rr][4], (a) + q1.x);                                \
    acc[rr][5] = fminf(acc[rr][5], (a) + q1.y);                                \
    acc[rr][6] = fminf(acc[rr][6], (a) + q1.z);                                \
    acc[rr][7] = fminf(acc[rr][7], (a) + q1.w);

#define KSTEP(comp, i) {                                                       \
        float4 q0 = B0[i], q1 = B1[i];                                         \
        _Pragma("unroll")                                                      \
        for (int rr = 0; rr < 8; ++rr) { COLS(rr, Aq[rr].comp, q0, q1) } }

#pragma unroll
    for (int kq = 0; kq < 16; ++kq) {
        int k0 = kq * 4;
        float4 Aq[8];
#pragma unroll
        for (int rr = 0; rr < 8; ++rr)
            Aq[rr] = *(const float4*)&As[(arow + rr) * 64 + (k0 ^ swzly)];
        float4 B0[4], B1[4];
#pragma unroll
        for (int kk = 0; kk < 4; ++kk) {
            B0[kk] = *(const float4*)&Bs[(k0 + kk) * 64 + bcol];
            B1[kk] = *(const float4*)&Bs[(k0 + kk) * 64 + bcol + 4];
        }
        KSTEP(x, 0) KSTEP(y, 1) KSTEP(z, 2) KSTEP(w, 3)
    }

    const size_t M = (size_t)B * N * N;
    float* O = Out + (size_t)ks * M;
#pragma unroll
    for (int rr = 0; rr < 8; ++rr) {
        int row = bofs + (bi64 + arow + rr) * N + bj64 + bcol;
        *(float4*)&O[row]     = make_float4(acc[rr][0], acc[rr][1], acc[rr][2], acc[rr][3]);
        *(float4*)&O[row + 4] = make_float4(acc[rr][4], acc[rr][5], acc[rr][6], acc[rr][7]);
    }
}

// ---------------------------------------------------------------------------
// per row (b,i): radix-select 32 smallest (value,index) keys from the 4-way
// min of partials; emit indices ascending == sort(stable_argsort(row)[:32]).
// ---------------------------------------------------------------------------
__global__ __launch_bounds__(256) void k_select(const float* __restrict__ D0,
                                                const float* __restrict__ D1,
                                                const float* __restrict__ D2,
                                                const float* __restrict__ D3,
                                                int* __restrict__ nbr) {
    int row = blockIdx.x;           // b*N + i
    int j = threadIdx.x;
    int lane = j & 63;
    int wid = j >> 6;

    __shared__ int wcnt[4], weq[4], wsel[4];

    int idx = row * N + j;
    float d = fminf(fminf(D0[idx], D1[idx]), fminf(D2[idx], D3[idx]));
    unsigned u = __float_as_uint(d);   // d >= 0 -> monotone bits

    unsigned prefix = 0;
    for (int bb = 31; bb >= 0; --bb) {
        unsigned cand = prefix | (1u << bb);
        unsigned long long m = __ballot(u < cand);
        if (lane == 0) wcnt[wid] = __popcll(m);
        __syncthreads();
        int c = wcnt[0] + wcnt[1] + wcnt[2] + wcnt[3];
        if (c <= 31) prefix = cand;
        __syncthreads();
    }

    unsigned long long mlt = __ballot(u < prefix);
    unsigned long long meq = __ballot(u == prefix);
    if (lane == 0) { wcnt[wid] = __popcll(mlt); weq[wid] = __popcll(meq); }
    __syncthreads();
    int cless = wcnt[0] + wcnt[1] + wcnt[2] + wcnt[3];
    int need = 32 - cless;
    int eqbefore = 0;
    for (int w = 0; w < wid; ++w) eqbefore += weq[w];
    int tie_rank = eqbefore + __popcll(meq & ((1ull << lane) - 1ull));
    bool flag = (u < prefix) || (u == prefix && tie_rank < need);

    unsigned long long msel = __ballot(flag);
    if (lane == 0) wsel[wid] = __popcll(msel);
    __syncthreads();
    int base = 0;
    for (int w = 0; w < wid; ++w) base += wsel[w];
    int pos = base + __popcll(msel & ((1ull << lane) - 1ull));
    if (flag) nbr[row * NB + pos] = j;
}

// ---------------------------------------------------------------------------
// fused gathers: blocks [0,16384) do features, [16384,32768) do adj+edge
// ---------------------------------------------------------------------------
__global__ __launch_bounds__(256) void k_gather(const float* __restrict__ feat,
                                                const float* __restrict__ adj,
                                                const float* __restrict__ ef,
                                                const int* __restrict__ nbr,
                                                float* __restrict__ outF,
                                                float* __restrict__ outA,
                                                float* __restrict__ outE) {
    int bidx = blockIdx.x;
    if (bidx < 16384) {
        int gid = bidx * 256 + threadIdx.x;    // B*N*NB*(F/4)
        int c4  = gid & 31;
        int r   = (gid >> 5) & 31;
        int row = gid >> 10;
        int b   = row >> 8;
        int nj = nbr[row * NB + r];
        float4 v = ld4(&feat[((b << 8) + nj) * F + (c4 << 2)]);
        ((float4*)outF)[gid] = v;
    } else {
        int gid = (bidx - 16384) * 256 + threadIdx.x;   // B*N*NB*NB
        int c   = gid & 31;
        int r   = (gid >> 5) & 31;
        int row = gid >> 10;
        int b   = row >> 8;
        int nr = nbr[row * NB + r];
        int nc = nbr[row * NB + c];
        int base = (b << 16) + (nr << 8) + nc;
        outA[gid] = adj[base];
        float3 e = *(const float3*)&ef[(long)base * 3];
        *(float3*)&outE[(long)gid * 3] = e;
    }
}

// ---------------------------------------------------------------------------
extern "C" void kernel_launch(void* const* d_in, const int* in_sizes, int n_in,
                              void* d_out, int out_size, void* d_ws, size_t ws_size,
                              hipStream_t stream) {
    const float* feat = (const float*)d_in[0];   // (B,N,F)
    const float* adj  = (const float*)d_in[1];   // (B,N,N)
    const float* ef   = (const float*)d_in[2];   // (B,N,N,3)

    float* out  = (float*)d_out;
    float* outF = out;                                   // B*N*NB*F
    float* outA = out + (size_t)B * N * NB * F;          // B*N*NB*NB
    float* outE = outA + (size_t)B * N * NB * NB;        // B*N*NB*NB*3

    const size_t M = (size_t)B * N * N;                  // 1,048,576
    // 8 partial buffers live in d_out (33.6 MB << 134 MB); dead before the
    // gathers overwrite the region. d_ws holds only nbr.
    float* W0 = out;             // 4 partials
    float* W1 = out + 4 * M;     // 4 partials
    int*  nbr = (int*)d_ws;

    // 8 squarings like the reference; each K-split x4, combined (exact min)
    // in the next consumer's staging loads.
    k_minplus<true><<<1024, 64, 0, stream>>>(adj, adj, adj, adj, W0);
    float* cur = W0;
    float* nxt = W1;
    for (int s = 1; s < 8; ++s) {
        k_minplus<false><<<1024, 64, 0, stream>>>(cur, cur + M, cur + 2 * M,
                                                  cur + 3 * M, nxt);
        float* t = cur; cur = nxt; nxt = t;
    }
    // final 4 partials in cur

    k_select<<<B * N, 256, 0, stream>>>(cur, cur + M, cur + 2 * M, cur + 3 * M,
                                        nbr);

    k_gather<<<32768, 256, 0, stream>>>(feat, adj, ef, nbr, outF, outA, outE);
}

// Round 5
// 182.303 us; speedup vs baseline: 1.8635x; 1.8635x over previous
//
#include <hip/hip_runtime.h>

#define B  16
#define N  256
#define F  128
#define NB 32
#define INF_F 1000000000.0f

__device__ __forceinline__ float xf(float v, int gi, int gk) {
    // where(adj>0, adj, INF) then diag=0 (diag wins), exactly like reference
    return (gi == gk) ? 0.0f : ((v > 0.0f) ? v : INF_F);
}
__device__ __forceinline__ float4 ld4(const float* p) { return *(const float4*)p; }
__device__ __forceinline__ float4 min4(float4 a, float4 b) {
    return make_float4(fminf(a.x, b.x), fminf(a.y, b.y),
                       fminf(a.z, b.z), fminf(a.w, b.w));
}

// ---------------------------------------------------------------------------
// min-plus squaring, K-split x4. Block (b,bi,bj,ks): 256 threads (4 waves),
// output tile 128x64 (rows bi*128.., cols bj*64..), k-chunk 64 (ks*64..),
// staged as two 32-k tiles, double-buffered. 8x4 acc per lane.
// S = XFORM(adj) on FIRST step, else min(P0..P3) (exact min reassociation).
// 512 blocks -> 2 blocks/CU -> 8 waves/CU -> 2 waves/SIMD.
// A stored [row][k] (stride 32) with XOR-quad swizzle (k' = k ^ ((row>>3&7)<<2))
// -> compute reads are 16-lane broadcast x 2-way (free). B stored [k][j] linear.
// ---------------------------------------------------------------------------
template<bool FIRST>
__global__ __launch_bounds__(256, 2) void k_minplus(const float* __restrict__ P0,
                                                    const float* __restrict__ P1,
                                                    const float* __restrict__ P2,
                                                    const float* __restrict__ P3,
                                                    float* __restrict__ Out) {
    int blk = blockIdx.x;            // ((b*2+bi)*4+bj)*4+ks, 512 total
    int ks = blk & 3;
    int bj = (blk >> 2) & 3;
    int bi = (blk >> 4) & 1;
    int b  = blk >> 5;
    const int bofs = b * N * N;
    const int kc = ks * 64;          // k-chunk base
    const int ri = bi * 128;         // tile row base
    const int cj = bj * 64;          // tile col base

    __shared__ __align__(16) float As[2][128 * 32];
    __shared__ __align__(16) float Bs[2][32 * 64];

    int tid = threadIdx.x;
    int ty = tid >> 4, tx = tid & 15;

    float4 ra[4][4], rb[2][4];       // staging regs [u][partial]

    // ---- issue global loads for k-tile kt (A: 4 quads/lane, B: 2 quads/lane)
#define LOADS(kt) {                                                            \
        int kbase = kc + (kt) * 32;                                            \
        _Pragma("unroll")                                                      \
        for (int u = 0; u < 4; ++u) {                                          \
            int lin4 = u * 256 + tid;                                          \
            int arow = lin4 >> 3, aqc = (lin4 & 7) << 2;                       \
            int idx = bofs + (ri + arow) * N + kbase + aqc;                    \
            ra[u][0] = ld4(P0 + idx);                                          \
            if (!FIRST) {                                                      \
                ra[u][1] = ld4(P1 + idx);                                      \
                ra[u][2] = ld4(P2 + idx);                                      \
                ra[u][3] = ld4(P3 + idx);                                      \
            }                                                                  \
        }                                                                      \
        _Pragma("unroll")                                                      \
        for (int u = 0; u < 2; ++u) {                                          \
            int lin4 = u * 256 + tid;                                          \
            int brow = lin4 >> 4, bqc = (lin4 & 15) << 2;                      \
            int idx = bofs + (kbase + brow) * N + cj + bqc;                    \
            rb[u][0] = ld4(P0 + idx);                                          \
            if (!FIRST) {                                                      \
                rb[u][1] = ld4(P1 + idx);                                      \
                rb[u][2] = ld4(P2 + idx);                                      \
                rb[u][3] = ld4(P3 + idx);                                      \
            }                                                                  \
        }                                                                      \
    }

    // ---- combine partials (or xform) and write LDS buffer bufi
#define COMMIT(kt, bufi) {                                                     \
        int kbase = kc + (kt) * 32;                                            \
        _Pragma("unroll")                                                      \
        for (int u = 0; u < 4; ++u) {                                          \
            int lin4 = u * 256 + tid;                                          \
            int arow = lin4 >> 3, aqc = (lin4 & 7) << 2;                       \
            float4 v;                                                          \
            if (FIRST) {                                                       \
                v = ra[u][0];                                                  \
                int gi = ri + arow, gk = kbase + aqc;                          \
                v.x = xf(v.x, gi, gk);     v.y = xf(v.y, gi, gk + 1);          \
                v.z = xf(v.z, gi, gk + 2); v.w = xf(v.w, gi, gk + 3);          \
            } else {                                                           \
                v = min4(min4(ra[u][0], ra[u][1]), min4(ra[u][2], ra[u][3]));  \
            }                                                                  \
            *(float4*)&As[bufi][arow * 32 + (aqc ^ (((arow >> 3) & 7) << 2))] = v; \
        }                                                                      \
        _Pragma("unroll")                                                      \
        for (int u = 0; u < 2; ++u) {                                          \
            int lin4 = u * 256 + tid;                                          \
            int brow = lin4 >> 4, bqc = (lin4 & 15) << 2;                      \
            float4 v;                                                          \
            if (FIRST) {                                                       \
                v = rb[u][0];                                                  \
                int gk = kbase + brow, gj = cj + bqc;                          \
                v.x = xf(v.x, gk, gj);     v.y = xf(v.y, gk, gj + 1);          \
                v.z = xf(v.z, gk, gj + 2); v.w = xf(v.w, gk, gj + 3);          \
            } else {                                                           \
                v = min4(min4(rb[u][0], rb[u][1]), min4(rb[u][2], rb[u][3]));  \
            }                                                                  \
            *(float4*)&Bs[bufi][brow * 64 + bqc] = v;                          \
        }                                                                      \
    }

    float acc[8][4];
#pragma unroll
    for (int r = 0; r < 8; ++r)
#pragma unroll
        for (int c = 0; c < 4; ++c) acc[r][c] = 3.0e38f;

    const int aswz = (ty & 7) << 2;  // == ((row>>3)&7)<<2 for rows ty*8..ty*8+7

#define KSTEP(comp, i) {                                                       \
        float4 q = Bq[i];                                                      \
        _Pragma("unroll")                                                      \
        for (int rr = 0; rr < 8; ++rr) {                                       \
            acc[rr][0] = fminf(acc[rr][0], Aq[rr].comp + q.x);                 \
            acc[rr][1] = fminf(acc[rr][1], Aq[rr].comp + q.y);                 \
            acc[rr][2] = fminf(acc[rr][2], Aq[rr].comp + q.z);                 \
            acc[rr][3] = fminf(acc[rr][3], Aq[rr].comp + q.w);                 \
        } }

#define COMPUTE(bufi) {                                                        \
        _Pragma("unroll")                                                      \
        for (int kq = 0; kq < 8; ++kq) {                                       \
            int k0 = kq * 4;                                                   \
            float4 Aq[8];                                                      \
            _Pragma("unroll")                                                  \
            for (int rr = 0; rr < 8; ++rr)                                     \
                Aq[rr] = *(const float4*)&As[bufi][(ty * 8 + rr) * 32 + (k0 ^ aswz)]; \
            float4 Bq[4];                                                      \
            _Pragma("unroll")                                                  \
            for (int kk = 0; kk < 4; ++kk)                                     \
                Bq[kk] = *(const float4*)&Bs[bufi][(k0 + kk) * 64 + tx * 4];   \
            KSTEP(x, 0) KSTEP(y, 1) KSTEP(z, 2) KSTEP(w, 3)                    \
        } }

    LOADS(0)
    COMMIT(0, 0)
    __syncthreads();
    LOADS(1)                 // issue early: latency hides under COMPUTE(0)
    COMPUTE(0)
    COMMIT(1, 1)
    __syncthreads();
    COMPUTE(1)

    const size_t M = (size_t)B * N * N;
    float* O = Out + (size_t)ks * M + bofs;
#pragma unroll
    for (int rr = 0; rr < 8; ++rr) {
        int row = ri + ty * 8 + rr;
        *(float4*)&O[row * N + cj + tx * 4] =
            make_float4(acc[rr][0], acc[rr][1], acc[rr][2], acc[rr][3]);
    }
}

// ---------------------------------------------------------------------------
// per row (b,i): radix-select 32 smallest (value,index) keys from the 4-way
// min of partials; emit indices ascending == sort(stable_argsort(row)[:32]).
// ---------------------------------------------------------------------------
__global__ __launch_bounds__(256) void k_select(const float* __restrict__ D0,
                                                const float* __restrict__ D1,
                                                const float* __restrict__ D2,
                                                const float* __restrict__ D3,
                                                int* __restrict__ nbr) {
    int row = blockIdx.x;           // b*N + i
    int j = threadIdx.x;
    int lane = j & 63;
    int wid = j >> 6;

    __shared__ int wcnt[4], weq[4], wsel[4];

    int idx = row * N + j;
    float d = fminf(fminf(D0[idx], D1[idx]), fminf(D2[idx], D3[idx]));
    unsigned u = __float_as_uint(d);   // d >= 0 -> monotone bits

    unsigned prefix = 0;
    for (int bb = 31; bb >= 0; --bb) {
        unsigned cand = prefix | (1u << bb);
        unsigned long long m = __ballot(u < cand);
        if (lane == 0) wcnt[wid] = __popcll(m);
        __syncthreads();
        int c = wcnt[0] + wcnt[1] + wcnt[2] + wcnt[3];
        if (c <= 31) prefix = cand;
        __syncthreads();
    }

    unsigned long long mlt = __ballot(u < prefix);
    unsigned long long meq = __ballot(u == prefix);
    if (lane == 0) { wcnt[wid] = __popcll(mlt); weq[wid] = __popcll(meq); }
    __syncthreads();
    int cless = wcnt[0] + wcnt[1] + wcnt[2] + wcnt[3];
    int need = 32 - cless;
    int eqbefore = 0;
    for (int w = 0; w < wid; ++w) eqbefore += weq[w];
    int tie_rank = eqbefore + __popcll(meq & ((1ull << lane) - 1ull));
    bool flag = (u < prefix) || (u == prefix && tie_rank < need);

    unsigned long long msel = __ballot(flag);
    if (lane == 0) wsel[wid] = __popcll(msel);
    __syncthreads();
    int base = 0;
    for (int w = 0; w < wid; ++w) base += wsel[w];
    int pos = base + __popcll(msel & ((1ull << lane) - 1ull));
    if (flag) nbr[row * NB + pos] = j;
}

// ---------------------------------------------------------------------------
// fused gathers: blocks [0,16384) do features, [16384,32768) do adj+edge
// ---------------------------------------------------------------------------
__global__ __launch_bounds__(256) void k_gather(const float* __restrict__ feat,
                                                const float* __restrict__ adj,
                                                const float* __restrict__ ef,
                                                const int* __restrict__ nbr,
                                                float* __restrict__ outF,
                                                float* __restrict__ outA,
                                                float* __restrict__ outE) {
    int bidx = blockIdx.x;
    if (bidx < 16384) {
        int gid = bidx * 256 + threadIdx.x;    // B*N*NB*(F/4)
        int c4  = gid & 31;
        int r   = (gid >> 5) & 31;
        int row = gid >> 10;
        int b   = row >> 8;
        int nj = nbr[row * NB + r];
        float4 v = ld4(&feat[((b << 8) + nj) * F + (c4 << 2)]);
        ((float4*)outF)[gid] = v;
    } else {
        int gid = (bidx - 16384) * 256 + threadIdx.x;   // B*N*NB*NB
        int c   = gid & 31;
        int r   = (gid >> 5) & 31;
        int row = gid >> 10;
        int b   = row >> 8;
        int nr = nbr[row * NB + r];
        int nc = nbr[row * NB + c];
        int base = (b << 16) + (nr << 8) + nc;
        outA[gid] = adj[base];
        float3 e = *(const float3*)&ef[(long)base * 3];
        *(float3*)&outE[(long)gid * 3] = e;
    }
}

// ---------------------------------------------------------------------------
extern "C" void kernel_launch(void* const* d_in, const int* in_sizes, int n_in,
                              void* d_out, int out_size, void* d_ws, size_t ws_size,
                              hipStream_t stream) {
    const float* feat = (const float*)d_in[0];   // (B,N,F)
    const float* adj  = (const float*)d_in[1];   // (B,N,N)
    const float* ef   = (const float*)d_in[2];   // (B,N,N,3)

    float* out  = (float*)d_out;
    float* outF = out;                                   // B*N*NB*F
    float* outA = out + (size_t)B * N * NB * F;          // B*N*NB*NB
    float* outE = outA + (size_t)B * N * NB * NB;        // B*N*NB*NB*3

    const size_t M = (size_t)B * N * N;                  // 1,048,576
    // 8 partial buffers live in d_out (33.6 MB << 134 MB); dead before the
    // gathers overwrite the region. d_ws holds only nbr.
    float* W0 = out;             // 4 partials
    float* W1 = out + 4 * M;     // 4 partials
    int*  nbr = (int*)d_ws;

    // 8 squarings like the reference; each K-split x4, partials combined
    // (exact min) in the next consumer's staging loads.
    k_minplus<true><<<512, 256, 0, stream>>>(adj, adj, adj, adj, W0);
    float* cur = W0;
    float* nxt = W1;
    for (int s = 1; s < 8; ++s) {
        k_minplus<false><<<512, 256, 0, stream>>>(cur, cur + M, cur + 2 * M,
                                                  cur + 3 * M, nxt);
        float* t = cur; cur = nxt; nxt = t;
    }
    // final 4 partials in cur

    k_select<<<B * N, 256, 0, stream>>>(cur, cur + M, cur + 2 * M, cur + 3 * M,
                                        nbr);

    k_gather<<<32768, 256, 0, stream>>>(feat, adj, ef, nbr, outF, outA, outE);
}